// Round 4
// baseline (64.578 us; speedup 1.0000x reference)
//
#include <hip/hip_runtime.h>

#define NPERS 64
#define NJOINT 15
#define NDEPTH 128
#define BIGF 100000.0f
#define EPSF 1e-8f
#define NQH 4            // q-split factor
#define QCHUNK (NPERS / NQH)
#define COEF_STRIDE 48   // floats per (b,q): w[15],c | wx[15],pad | wy[15],pad

// ---------------- precompute: per-(b,q) matching coefficients ----------------
// w_j  = vis*inv ; c = (sum (rx^2+ry^2)*vis)*inv ; wx_j = 2*vis*rx*inv ; wy_j = 2*vis*ry*inv
// dist(p,d,q) = sum_j P2_j*w_j + c - sum_j X_j*wx_j - sum_j Y_j*wy_j
__global__ __launch_bounds__(256) void coef_kernel(
    const float* __restrict__ p2d,   // (B,NP,NJ,2)
    const float* __restrict__ vis,   // (B,NP,NJ)
    float* __restrict__ coef,        // (B,NP,48)
    int total)                       // B*NPERS
{
    int t = blockIdx.x * 256 + threadIdx.x;
    if (t >= total) return;
    // t = b*NPERS + q
    float v[NJOINT], rx[NJOINT], ry[NJOINT];
    float vs = 0.0f, t2 = 0.0f;
    #pragma unroll
    for (int j = 0; j < NJOINT; ++j) {
        v[j]  = vis[t * NJOINT + j];
        rx[j] = p2d[(t * NJOINT + j) * 2 + 0];
        ry[j] = p2d[(t * NJOINT + j) * 2 + 1];
        vs += v[j];
        t2 = fmaf(rx[j] * rx[j] + ry[j] * ry[j], v[j], t2);
    }
    float inv = 1.0f / (vs + EPSF);
    float* o = coef + (size_t)t * COEF_STRIDE;
    #pragma unroll
    for (int j = 0; j < NJOINT; ++j) {
        o[j]      = v[j] * inv;
        o[16 + j] = 2.0f * v[j] * rx[j] * inv;
        o[32 + j] = 2.0f * v[j] * ry[j] * inv;
    }
    o[15] = t2 * inv;
    o[31] = 0.0f;
    o[47] = 0.0f;
}

// ---------------- main fused kernel ----------------
__global__ __launch_bounds__(512, 3) void pose_match_kernel(
    const float* __restrict__ poses_3d,   // (B,NP,NJ,ND,3)
    const float* __restrict__ p2d,        // (B,NP,NJ,2)
    const float* __restrict__ vis,        // (B,NP,NJ)
    const int*   __restrict__ nper,       // (B,)
    const float* __restrict__ Rm,         // (B,3,3)
    const float* __restrict__ Tm,         // (B,3)
    const float* __restrict__ fm,         // (B,2)
    const float* __restrict__ cm,         // (B,2)
    const float* __restrict__ iw_,        // (B,)
    const float* __restrict__ ih_,        // (B,)
    const float* __restrict__ coef,       // (B,NP,48) packed coefficients
    float* __restrict__ out)              // (B,NP,NJ,ND)
{
    const int b   = blockIdx.x / NPERS;
    const int p   = blockIdx.x % NPERS;
    const int tid = threadIdx.x;
    const int qh  = tid >> 7;     // 0..3: which 16-candidate slice
    const int d   = tid & 127;    // depth bin

    __shared__ float4 sq[NPERS][NJOINT];   // {vis, rx, ry, unused} -- phase-2 only
    __shared__ float bvred[NQH][NDEPTH];
    __shared__ int   bqred[NQH][NDEPTH];

    // ---- stage per-batch candidate data into LDS (phase-2 lookup table) ----
    for (int i = tid; i < NPERS * NJOINT; i += 512) {
        int q = i / NJOINT, j = i % NJOINT;
        float v  = vis[(b * NPERS + q) * NJOINT + j];
        float rx = p2d[((b * NPERS + q) * NJOINT + j) * 2 + 0];
        float ry = p2d[((b * NPERS + q) * NJOINT + j) * 2 + 1];
        sq[q][j] = make_float4(v, rx, ry, 0.0f);
    }
    __syncthreads();

    // ---- camera params (wave-uniform) ----
    const float R00 = Rm[b*9+0], R01 = Rm[b*9+1], R02 = Rm[b*9+2];
    const float R10 = Rm[b*9+3], R11 = Rm[b*9+4], R12 = Rm[b*9+5];
    const float R20 = Rm[b*9+6], R21 = Rm[b*9+7], R22 = Rm[b*9+8];
    const float T0 = Tm[b*3+0], T1 = Tm[b*3+1], T2 = Tm[b*3+2];
    const float fx = fm[b*2+0], fy = fm[b*2+1];
    const float cx = cm[b*2+0], cy = cm[b*2+1];
    const float iwm1 = iw_[b] - 1.0f;
    const float ihm1 = ih_[b] - 1.0f;
    const int   npv  = nper[b];

    // ---- project this thread's 15 joints (duplicated across the 4 qh) ----
    float X[NJOINT], Y[NJOINT], P2[NJOINT];
    #pragma unroll
    for (int j = 0; j < NJOINT; ++j) {
        int base = (((b * NPERS + p) * NJOINT + j) * NDEPTH + d) * 3;
        float a0 = poses_3d[base + 0] - T0;
        float a1 = poses_3d[base + 1] - T1;
        float a2 = poses_3d[base + 2] - T2;
        float xc0 = R00 * a0 + R01 * a1 + R02 * a2;
        float xc1 = R10 * a0 + R11 * a1 + R12 * a2;
        float xc2 = R20 * a0 + R21 * a1 + R22 * a2;
        float xx = fx * xc0 / xc2 + cx;
        float yy = fy * xc1 / xc2 + cy;
        X[j] = xx; Y[j] = yy;
        P2[j] = xx * xx + yy * yy;
    }

    // ---- partial argmin over this thread's 16-candidate slice ----
    // coeff reads are wave-uniform from const global -> scalar/L1 path, no LDS
    float bestv = 3.0e38f;
    int   bestq = qh * QCHUNK;
    const int q0 = qh * QCHUNK;
    const float* cb = coef + (size_t)(b * NPERS) * COEF_STRIDE;
    for (int q = q0; q < q0 + QCHUNK; ++q) {
        const float* cq = cb + q * COEF_STRIDE;
        float s1 = cq[15];              // c
        float sx = 0.0f, sy = 0.0f;
        #pragma unroll
        for (int j = 0; j < NJOINT; ++j) {
            s1 = fmaf(P2[j], cq[j],      s1);
            sx = fmaf(X[j],  cq[16 + j], sx);
            sy = fmaf(Y[j],  cq[32 + j], sy);
        }
        float dist = s1 - sx - sy;
        dist = (q < npv) ? dist : BIGF;
        if (dist < bestv) { bestv = dist; bestq = q; }
    }
    bvred[qh][d] = bestv;
    bqred[qh][d] = bestq;
    __syncthreads();

    // ---- combine partials (ascending qh, strict <  => np.argmin tie-break)
    //      and run phase 2 on the qh==0 slice ----
    if (qh == 0) {
        #pragma unroll
        for (int k = 1; k < NQH; ++k) {
            float v = bvred[k][d];
            if (v < bestv) { bestv = v; bestq = bqred[k][d]; }
        }
        const int obase = ((b * NPERS + p) * NJOINT) * NDEPTH + d;
        #pragma unroll
        for (int j = 0; j < NJOINT; ++j) {
            float4 v = sq[bestq][j];
            float dx = X[j] - v.y;
            float dy = Y[j] - v.z;
            float md = fmaf(dx, dx, dy * dy);
            float sc = expf(-md * (1.0f / 225.0f));
            float inb = (X[j] >= 0.0f && Y[j] >= 0.0f &&
                         X[j] <= iwm1 && Y[j] <= ihm1) ? 1.0f : 0.0f;
            out[obase + j * NDEPTH] = sc * inb * v.x;
        }
    }
}

extern "C" void kernel_launch(void* const* d_in, const int* in_sizes, int n_in,
                              void* d_out, int out_size, void* d_ws, size_t ws_size,
                              hipStream_t stream) {
    const float* poses_3d = (const float*)d_in[0];
    const float* p2d      = (const float*)d_in[1];
    const float* vis      = (const float*)d_in[2];
    const int*   nper     = (const int*)d_in[3];
    const float* Rm       = (const float*)d_in[4];
    const float* Tm       = (const float*)d_in[5];
    const float* fm       = (const float*)d_in[6];
    const float* cm       = (const float*)d_in[7];
    const float* iw       = (const float*)d_in[8];
    const float* ih       = (const float*)d_in[9];
    float* out  = (float*)d_out;
    float* coef = (float*)d_ws;            // B*NPERS*48 floats = 192 KiB

    const int B = in_sizes[3];  // num_persons_ref has B elements
    const int total = B * NPERS;

    coef_kernel<<<(total + 255) / 256, 256, 0, stream>>>(p2d, vis, coef, total);

    dim3 grid(B * NPERS);
    dim3 block(512);
    pose_match_kernel<<<grid, block, 0, stream>>>(
        poses_3d, p2d, vis, nper, Rm, Tm, fm, cm, iw, ih, coef, out);
}

// Round 6
// 34.144 us; speedup vs baseline: 1.8913x; 1.8913x over previous
//
#include <hip/hip_runtime.h>

#define NPERS 64
#define NJOINT 15
#define NDEPTH 128
#define BIGF 100000.0f
#define EPSF 1e-8f
#define NQH 4            // q-split factor
#define QCHUNK (NPERS / NQH)
#define COEF_STRIDE 48   // floats per (b,q): w[15],c | wx[15],pad | wy[15],pad

typedef float f32x16 __attribute__((ext_vector_type(16)));

// ---------------- precompute: per-(b,q) matching coefficients ----------------
// w_j  = vis*inv ; c = (sum (rx^2+ry^2)*vis)*inv ; wx_j = 2*vis*rx*inv ; wy_j = 2*vis*ry*inv
// dist(p,d,q) = sum_j P2_j*w_j + c - sum_j X_j*wx_j - sum_j Y_j*wy_j
__global__ __launch_bounds__(256) void coef_kernel(
    const float* __restrict__ p2d,   // (B,NP,NJ,2)
    const float* __restrict__ vis,   // (B,NP,NJ)
    float* __restrict__ coef,        // (B,NP,48)
    int total)                       // B*NPERS
{
    int t = blockIdx.x * 256 + threadIdx.x;
    if (t >= total) return;
    float v[NJOINT], rx[NJOINT], ry[NJOINT];
    float vs = 0.0f, t2 = 0.0f;
    #pragma unroll
    for (int j = 0; j < NJOINT; ++j) {
        v[j]  = vis[t * NJOINT + j];
        rx[j] = p2d[(t * NJOINT + j) * 2 + 0];
        ry[j] = p2d[(t * NJOINT + j) * 2 + 1];
        vs += v[j];
        t2 = fmaf(rx[j] * rx[j] + ry[j] * ry[j], v[j], t2);
    }
    float inv = 1.0f / (vs + EPSF);
    float* o = coef + (size_t)t * COEF_STRIDE;
    #pragma unroll
    for (int j = 0; j < NJOINT; ++j) {
        o[j]      = v[j] * inv;
        o[16 + j] = 2.0f * v[j] * rx[j] * inv;
        o[32 + j] = 2.0f * v[j] * ry[j] * inv;
    }
    o[15] = t2 * inv;
    o[31] = 0.0f;
    o[47] = 0.0f;
}

// ---------------- main fused kernel ----------------
__global__ __launch_bounds__(512, 6) void pose_match_kernel(
    const float* __restrict__ poses_3d,   // (B,NP,NJ,ND,3)
    const float* __restrict__ p2d,        // (B,NP,NJ,2)
    const float* __restrict__ vis,        // (B,NP,NJ)
    const int*   __restrict__ nper,       // (B,)
    const float* __restrict__ Rm,         // (B,3,3)
    const float* __restrict__ Tm,         // (B,3)
    const float* __restrict__ fm,         // (B,2)
    const float* __restrict__ cm,         // (B,2)
    const float* __restrict__ iw_,        // (B,)
    const float* __restrict__ ih_,        // (B,)
    const float* __restrict__ coef,       // (B,NP,48) packed coefficients
    float* __restrict__ out)              // (B,NP,NJ,ND)
{
    const int b   = blockIdx.x / NPERS;
    const int p   = blockIdx.x % NPERS;
    const int tid = threadIdx.x;
    // physically wave-uniform (waves = 64 consecutive tids); readfirstlane
    // makes it PROVABLY uniform so coefficient addresses live in SGPRs.
    const int qh  = __builtin_amdgcn_readfirstlane(tid >> 7);  // 0..3
    const int d   = tid & 127;                                  // depth bin

    __shared__ float4 sq[NPERS][NJOINT];   // {vis, rx, ry, _} -- phase-2 only
    __shared__ float bvred[NQH][NDEPTH];
    __shared__ int   bqred[NQH][NDEPTH];

    // ---- stage per-batch candidate data into LDS (phase-2 lookup table) ----
    for (int i = tid; i < NPERS * NJOINT; i += 512) {
        int q = i / NJOINT, j = i % NJOINT;
        float v  = vis[(b * NPERS + q) * NJOINT + j];
        float rx = p2d[((b * NPERS + q) * NJOINT + j) * 2 + 0];
        float ry = p2d[((b * NPERS + q) * NJOINT + j) * 2 + 1];
        sq[q][j] = make_float4(v, rx, ry, 0.0f);
    }
    __syncthreads();

    // ---- camera params (wave-uniform) ----
    const float R00 = Rm[b*9+0], R01 = Rm[b*9+1], R02 = Rm[b*9+2];
    const float R10 = Rm[b*9+3], R11 = Rm[b*9+4], R12 = Rm[b*9+5];
    const float R20 = Rm[b*9+6], R21 = Rm[b*9+7], R22 = Rm[b*9+8];
    const float T0 = Tm[b*3+0], T1 = Tm[b*3+1], T2 = Tm[b*3+2];
    const float fx = fm[b*2+0], fy = fm[b*2+1];
    const float cx = cm[b*2+0], cy = cm[b*2+1];
    const float iwm1 = iw_[b] - 1.0f;
    const float ihm1 = ih_[b] - 1.0f;
    const int   npv  = nper[b];

    // ---- project this thread's 15 joints (duplicated across the 4 qh) ----
    float X[NJOINT], Y[NJOINT], P2[NJOINT];
    #pragma unroll
    for (int j = 0; j < NJOINT; ++j) {
        int base = (((b * NPERS + p) * NJOINT + j) * NDEPTH + d) * 3;
        float a0 = poses_3d[base + 0] - T0;
        float a1 = poses_3d[base + 1] - T1;
        float a2 = poses_3d[base + 2] - T2;
        float xc0 = R00 * a0 + R01 * a1 + R02 * a2;
        float xc1 = R10 * a0 + R11 * a1 + R12 * a2;
        float xc2 = R20 * a0 + R21 * a1 + R22 * a2;
        float xx = fx * xc0 / xc2 + cx;
        float yy = fy * xc1 / xc2 + cy;
        X[j] = xx; Y[j] = yy;
        P2[j] = xx * xx + yy * yy;
    }

    // ---- partial argmin over this wave's 16-candidate slice ----
    // coefficients arrive via s_load_dwordx16 into SGPRs: zero LDS/VMEM
    // traffic, FMAs use the (free) scalar operand slot.
    // "=&s" EARLY-CLOBBER is essential: without it the allocator may
    // overlap an output tuple with the address pair %3, which the async
    // s_loads still need (R5 core-dump root cause).
    float bestv = 3.0e38f;
    int   bestq = qh * QCHUNK;
    const int q0 = qh * QCHUNK;
    const float* cb = coef + (size_t)(b * NPERS) * COEF_STRIDE;
    #pragma unroll 1
    for (int q = q0; q < q0 + QCHUNK; ++q) {
        const float* cq = cb + q * COEF_STRIDE;   // uniform -> SGPR pair
        f32x16 c0, c1, c2;
        asm volatile(
            "s_load_dwordx16 %0, %3, 0x0\n\t"
            "s_load_dwordx16 %1, %3, 0x40\n\t"
            "s_load_dwordx16 %2, %3, 0x80\n\t"
            "s_waitcnt lgkmcnt(0)"
            : "=&s"(c0), "=&s"(c1), "=&s"(c2)
            : "s"(cq));
        float s1 = c0[15];              // c term
        float sx = 0.0f, sy = 0.0f;
        #pragma unroll
        for (int j = 0; j < NJOINT; ++j) {
            s1 = fmaf(P2[j], c0[j], s1);
            sx = fmaf(X[j],  c1[j], sx);
            sy = fmaf(Y[j],  c2[j], sy);
        }
        float dist = s1 - sx - sy;
        dist = (q < npv) ? dist : BIGF;
        if (dist < bestv) { bestv = dist; bestq = q; }
    }
    bvred[qh][d] = bestv;
    bqred[qh][d] = bestq;
    __syncthreads();

    // ---- combine partials (ascending qh, strict <  => np.argmin tie-break)
    //      and run phase 2 on the qh==0 slice ----
    if (qh == 0) {
        #pragma unroll
        for (int k = 1; k < NQH; ++k) {
            float v = bvred[k][d];
            if (v < bestv) { bestv = v; bestq = bqred[k][d]; }
        }
        const int obase = ((b * NPERS + p) * NJOINT) * NDEPTH + d;
        #pragma unroll
        for (int j = 0; j < NJOINT; ++j) {
            float4 v = sq[bestq][j];
            float dx = X[j] - v.y;
            float dy = Y[j] - v.z;
            float md = fmaf(dx, dx, dy * dy);
            float sc = expf(-md * (1.0f / 225.0f));
            float inb = (X[j] >= 0.0f && Y[j] >= 0.0f &&
                         X[j] <= iwm1 && Y[j] <= ihm1) ? 1.0f : 0.0f;
            out[obase + j * NDEPTH] = sc * inb * v.x;
        }
    }
}

extern "C" void kernel_launch(void* const* d_in, const int* in_sizes, int n_in,
                              void* d_out, int out_size, void* d_ws, size_t ws_size,
                              hipStream_t stream) {
    const float* poses_3d = (const float*)d_in[0];
    const float* p2d      = (const float*)d_in[1];
    const float* vis      = (const float*)d_in[2];
    const int*   nper     = (const int*)d_in[3];
    const float* Rm       = (const float*)d_in[4];
    const float* Tm       = (const float*)d_in[5];
    const float* fm       = (const float*)d_in[6];
    const float* cm       = (const float*)d_in[7];
    const float* iw       = (const float*)d_in[8];
    const float* ih       = (const float*)d_in[9];
    float* out  = (float*)d_out;
    float* coef = (float*)d_ws;            // B*NPERS*48 floats = 192 KiB

    const int B = in_sizes[3];  // num_persons_ref has B elements
    const int total = B * NPERS;

    coef_kernel<<<(total + 255) / 256, 256, 0, stream>>>(p2d, vis, coef, total);

    dim3 grid(B * NPERS);
    dim3 block(512);
    pose_match_kernel<<<grid, block, 0, stream>>>(
        poses_3d, p2d, vis, nper, Rm, Tm, fm, cm, iw, ih, coef, out);
}